// Round 13
// baseline (409.504 us; speedup 1.0000x reference)
//
#include <hip/hip_runtime.h>
#include <hip/hip_fp16.h>
#include <math.h>

#define N_GRAPHS 100
#define HCHUNK 32768
#define HBLK 64

typedef _Float16 f16x8 __attribute__((ext_vector_type(8)));
typedef __attribute__((ext_vector_type(4))) float f32x4;

__device__ __forceinline__ float lrelu(float v) { return v >= 0.f ? v : 0.1f * v; }

// ---------------- prep: wfold/cval + W1/W2 -> transposed+swizzled fp16 ----------------
__global__ void k_prep(const float* __restrict__ W1, const float* __restrict__ W2,
                       const float* __restrict__ W3, const float* __restrict__ b3,
                       const float* __restrict__ Wout, const float* __restrict__ bout,
                       __half* __restrict__ w1T, __half* __restrict__ w2T,
                       float* __restrict__ wfold, float* __restrict__ cval) {
    if (blockIdx.x == 0) {
        int i = threadIdx.x;
        if (i < 128) {
            float s = 0.f;
            for (int j = 0; j < 64; ++j) s += W3[i * 64 + j] * Wout[j];
            wfold[i] = s;
            if (i == 0) {
                float c = bout[0];
                for (int j = 0; j < 64; ++j) c += b3[j] * Wout[j];
                *cval = c;
            }
        }
    } else {
        const float* W = (blockIdx.x == 1) ? W1 : W2;
        __half* wT = (blockIdx.x == 1) ? w1T : w2T;
        for (int i = threadIdx.x; i < 16384; i += 256) {
            int k = i >> 7, col = i & 127;
            wT[col * 128 + (k ^ ((col & 15) << 3))] = __float2half(W[i]);
        }
    }
}

// ---------------- combined src+dst chunked LDS histograms (u32 bins) -> u8 ----------
__global__ __launch_bounds__(512, 1)
void k_hist2(const int* __restrict__ src, const int* __restrict__ dst,
             unsigned char* __restrict__ ssrc, unsigned char* __restrict__ sdst,
             int E, int half) {
    __shared__ int h[HCHUNK];   // 128 KiB
    int id = blockIdx.x;
    const int* keys;
    unsigned char* outbase;
    if (id < half) { keys = dst; outbase = sdst; }
    else           { keys = src; outbase = ssrc; id -= half; }
    const int c = id / HBLK;
    const int b = id % HBLK;
    const int base = c * HCHUNK;
    for (int i = threadIdx.x; i < HCHUNK; i += 512) h[i] = 0;
    __syncthreads();
    for (int i = b * 512 + threadIdx.x; i < E; i += HBLK * 512) {
        unsigned k = (unsigned)(keys[i] - base);
        if (k < HCHUNK) atomicAdd(&h[k], 1);
    }
    __syncthreads();
    unsigned char* outp = outbase + (size_t)(c * HBLK + b) * HCHUNK;
    for (int i = threadIdx.x; i < HCHUNK; i += 512) outp[i] = (unsigned char)h[i];
}

// ---------------- merged: degree reduce (u8) + dinvs + scanA ----------------
__global__ void k_reduce_scan(const unsigned char* __restrict__ ssrc,
                              const unsigned char* __restrict__ sdst,
                              float* __restrict__ dsrc, float* __restrict__ ddst,
                              int* __restrict__ off, int* __restrict__ partials, int N) {
    __shared__ int ts[256];
    const int t = threadIdx.x;
    const int base = blockIdx.x * 1024 + t * 4;
    int v[4];
#pragma unroll
    for (int q = 0; q < 4; ++q) {
        int g = base + q;
        int s2 = 0;
        if (g < N) {
            const int c = g >> 15;
            const int p = g & (HCHUNK - 1);
            const unsigned char* cs = ssrc + (size_t)(c * HBLK) * HCHUNK + p;
            const unsigned char* cd = sdst + (size_t)(c * HBLK) * HCHUNK + p;
            int s1 = 0;
#pragma unroll 8
            for (int b = 0; b < HBLK; ++b) {
                s1 += cs[(size_t)b * HCHUNK];
                s2 += cd[(size_t)b * HCHUNK];
            }
            dsrc[g] = rsqrtf(fmaxf((float)s1, 1.0f));
            ddst[g] = rsqrtf(fmaxf((float)s2, 1.0f));
        }
        v[q] = s2;
    }
    int s = v[0] + v[1] + v[2] + v[3];
    ts[t] = s;
    __syncthreads();
    for (int o = 1; o < 256; o <<= 1) {
        int y = (t >= o) ? ts[t - o] : 0;
        __syncthreads();
        ts[t] += y;
        __syncthreads();
    }
    int excl = ts[t] - s;
    if (base + 0 < N) off[base + 0] = excl;
    if (base + 1 < N) off[base + 1] = excl + v[0];
    if (base + 2 < N) off[base + 2] = excl + v[0] + v[1];
    if (base + 3 < N) off[base + 3] = excl + v[0] + v[1] + v[2];
    if (t == 255) partials[blockIdx.x] = ts[255];
}

// ---------------- merged: u8 column prefix over blocks + scanB (last block) ----------
__global__ void k_colscan_scanB(unsigned char* __restrict__ sdst, int NBINS,
                                int* __restrict__ partials, int nb,
                                float* __restrict__ gsum, float* __restrict__ gcnt) {
    if (blockIdx.x == gridDim.x - 1) {
        __shared__ int ps[256];
        const int t = threadIdx.x;
        if (t < N_GRAPHS) { gsum[t] = 0.f; gcnt[t] = 0.f; }
        int v = (t < nb) ? partials[t] : 0;
        ps[t] = v;
        __syncthreads();
        for (int o = 1; o < 256; o <<= 1) {
            int y = (t >= o) ? ps[t - o] : 0;
            __syncthreads();
            ps[t] += y;
            __syncthreads();
        }
        if (t < nb) partials[t] = ps[t] - v;
        return;
    }
    int g = blockIdx.x * blockDim.x + threadIdx.x;
    if (g >= NBINS) return;
    const int c = g >> 15;
    const int p = g & (HCHUNK - 1);
    unsigned char* col = sdst + (size_t)(c * HBLK) * HCHUNK + p;
    int run = 0;
    for (int b = 0; b < HBLK; ++b) {
        unsigned char* q = col + (size_t)b * HCHUNK;
        int t = *q;
        *q = (unsigned char)run;
        run += t;
    }
}

__global__ void k_scanC(int* __restrict__ off, const int* __restrict__ partials, int N, int E) {
    const int t = threadIdx.x;
    const int base = blockIdx.x * 1024 + t * 4;
    const int add = partials[blockIdx.x];
#pragma unroll
    for (int q = 0; q < 4; ++q) {
        int idx = base + q;
        if (idx < N) off[idx] += add;
    }
    if (blockIdx.x == 0 && t == 0) off[N] = E;
}

// ---------------- CSR fill via LDS cursors (cursor = off + u8 prefix) ----------------
__global__ __launch_bounds__(512, 1)
void k_csrfill2(const int* __restrict__ src, const int* __restrict__ dst,
                const unsigned char* __restrict__ pref, const int* __restrict__ off,
                int* __restrict__ csr, int E, int N) {
    __shared__ int cur[HCHUNK];   // 128 KiB
    const int c = blockIdx.x / HBLK;
    const int b = blockIdx.x % HBLK;
    const int base = c * HCHUNK;
    const unsigned char* my = pref + (size_t)(c * HBLK + b) * HCHUNK;
    for (int i = threadIdx.x; i < HCHUNK; i += 512) {
        int g = base + i;
        cur[i] = ((g < N) ? off[g] : 0) + (int)my[i];
    }
    __syncthreads();
    for (int i = b * 512 + threadIdx.x; i < E; i += HBLK * 512) {
        unsigned k = (unsigned)(dst[i] - base);
        if (k < HCHUNK) {
            int p = atomicAdd(&cur[k], 1);
            csr[p] = src[i];
        }
    }
}

// ---------------- layer-1 GEMM (fp32 in, prenorm, Ws staged in LDS) ----------------
__global__ __launch_bounds__(512, 2)
void k_gemm1(const float* __restrict__ X, __half* __restrict__ Y,
             const __half* __restrict__ wT, const float* __restrict__ dinv_src, int N) {
    __shared__ __half Xs[128 * 128];  // 32 KiB
    __shared__ __half Ws[128 * 128];  // 32 KiB
    const int t = threadIdx.x;
    const int r0 = blockIdx.x * 128;

    for (int i = t; i < 2048; i += 512) ((float4*)Ws)[i] = ((const float4*)wT)[i];

    for (int i = t; i < 4096; i += 512) {
        int row = i >> 5;
        int g4 = (i & 31) << 2;
        int grow = r0 + row;
        float4 v = make_float4(0.f, 0.f, 0.f, 0.f);
        if (grow < N) {
            v = ((const float4*)(X + (size_t)grow * 128))[i & 31];
            float ds = dinv_src[grow];
            v.x *= ds; v.y *= ds; v.z *= ds; v.w *= ds;
        }
        union { float2 f; __half2 h[2]; } pk;
        pk.h[0] = __floats2half2_rn(v.x, v.y);
        pk.h[1] = __floats2half2_rn(v.z, v.w);
        *(float2*)&Xs[row * 128 + (g4 ^ ((row & 15) << 3))] = pk.f;
    }
    __syncthreads();

    const int w = t >> 6;
    const int wm = w & 3;
    const int wn = w >> 2;
    const int lane = t & 63;
    const int lr = lane & 15;
    const int lg = lane >> 4;

    f32x4 acc[2][4];
#pragma unroll
    for (int mi = 0; mi < 2; ++mi)
#pragma unroll
        for (int ni = 0; ni < 4; ++ni) acc[mi][ni] = (f32x4){0.f, 0.f, 0.f, 0.f};

#pragma unroll
    for (int ks = 0; ks < 4; ++ks) {
        const int k0 = 32 * ks + 4 * lg;
        union F { float2 f[2]; f16x8 v; };
        F a[2];
#pragma unroll
        for (int mi = 0; mi < 2; ++mi) {
            int row = 32 * wm + 16 * mi + lr;
            int sw = (row & 15) << 3;
            a[mi].f[0] = *(const float2*)&Xs[row * 128 + (k0 ^ sw)];
            a[mi].f[1] = *(const float2*)&Xs[row * 128 + ((k0 + 16) ^ sw)];
        }
#pragma unroll
        for (int ni = 0; ni < 4; ++ni) {
            int colv = 64 * wn + 16 * ni + lr;
            int sw = (colv & 15) << 3;
            F b;
            b.f[0] = *(const float2*)&Ws[colv * 128 + (k0 ^ sw)];
            b.f[1] = *(const float2*)&Ws[colv * 128 + ((k0 + 16) ^ sw)];
#pragma unroll
            for (int mi = 0; mi < 2; ++mi)
                acc[mi][ni] = __builtin_amdgcn_mfma_f32_16x16x32_f16(a[mi].v, b.v, acc[mi][ni], 0, 0, 0);
        }
    }

    __syncthreads();
#pragma unroll
    for (int mi = 0; mi < 2; ++mi)
#pragma unroll
        for (int r = 0; r < 4; ++r) {
            int row = 32 * wm + 16 * mi + 4 * lg + r;
#pragma unroll
            for (int ni = 0; ni < 4; ++ni)
                Xs[row * 128 + 64 * wn + 16 * ni + lr] = __float2half(acc[mi][ni][r]);
        }
    __syncthreads();
    for (int i = t; i < 2048; i += 512) {
        int row = i >> 4;
        int grow = r0 + row;
        if (grow < N) {
            int col8 = (i & 15) << 3;
            *(uint4*)(Y + (size_t)grow * 128 + col8) = *(const uint4*)&Xs[row * 128 + col8];
        }
    }
}

// ---------------- layers 2/3 GEMM (fp16 in, B-fragments direct from L1/L2-hot wT) ----
__global__ __launch_bounds__(512, 2)
void k_gemm2(const __half* __restrict__ X, __half* __restrict__ Y,
             const __half* __restrict__ wT, int N) {
    __shared__ __half Xs[128 * 128];  // 32 KiB only
    const int t = threadIdx.x;
    const int r0 = blockIdx.x * 128;

    for (int i = t; i < 2048; i += 512) {
        int row = i >> 4;
        int g8 = (i & 15) << 3;
        int grow = r0 + row;
        uint4 v = make_uint4(0u, 0u, 0u, 0u);
        if (grow < N) v = ((const uint4*)(X + (size_t)grow * 128))[i & 15];
        *(uint4*)&Xs[row * 128 + (g8 ^ ((row & 15) << 3))] = v;
    }
    __syncthreads();

    const int w = t >> 6;
    const int wm = w & 3;
    const int wn = w >> 2;
    const int lane = t & 63;
    const int lr = lane & 15;
    const int lg = lane >> 4;

    f32x4 acc[2][4];
#pragma unroll
    for (int mi = 0; mi < 2; ++mi)
#pragma unroll
        for (int ni = 0; ni < 4; ++ni) acc[mi][ni] = (f32x4){0.f, 0.f, 0.f, 0.f};

#pragma unroll
    for (int ks = 0; ks < 4; ++ks) {
        const int k0 = 32 * ks + 4 * lg;
        union F { float2 f[2]; f16x8 v; };
        F a[2];
#pragma unroll
        for (int mi = 0; mi < 2; ++mi) {
            int row = 32 * wm + 16 * mi + lr;
            int sw = (row & 15) << 3;
            a[mi].f[0] = *(const float2*)&Xs[row * 128 + (k0 ^ sw)];
            a[mi].f[1] = *(const float2*)&Xs[row * 128 + ((k0 + 16) ^ sw)];
        }
#pragma unroll
        for (int ni = 0; ni < 4; ++ni) {
            int colv = 64 * wn + 16 * ni + lr;
            int sw = (colv & 15) << 3;
            F b;
            b.f[0] = *(const float2*)&wT[colv * 128 + (k0 ^ sw)];        // L1/L2-hot
            b.f[1] = *(const float2*)&wT[colv * 128 + ((k0 + 16) ^ sw)];
#pragma unroll
            for (int mi = 0; mi < 2; ++mi)
                acc[mi][ni] = __builtin_amdgcn_mfma_f32_16x16x32_f16(a[mi].v, b.v, acc[mi][ni], 0, 0, 0);
        }
    }

    __syncthreads();
#pragma unroll
    for (int mi = 0; mi < 2; ++mi)
#pragma unroll
        for (int r = 0; r < 4; ++r) {
            int row = 32 * wm + 16 * mi + 4 * lg + r;
#pragma unroll
            for (int ni = 0; ni < 4; ++ni)
                Xs[row * 128 + 64 * wn + 16 * ni + lr] = __float2half(acc[mi][ni][r]);
        }
    __syncthreads();
    for (int i = t; i < 2048; i += 512) {
        int row = i >> 4;
        int grow = r0 + row;
        if (grow < N) {
            int col8 = (i & 15) << 3;
            *(uint4*)(Y + (size_t)grow * 128 + col8) = *(const uint4*)&Xs[row * 128 + col8];
        }
    }
}

// ---------------- CSR gather (fp16 msgs), half-wave per node, 4-edge unroll ----------
// EPI==0: H[n] = fp16( lrelu(agg*ddst + bias) * dsrc )
// EPI==1: tv[n] = dsrc * ( lrelu(agg*ddst + bias) . wfold )
template <int EPI>
__global__ __launch_bounds__(256)
void k_gather_h(const __half* __restrict__ T, __half* __restrict__ Hout,
                const int* __restrict__ csr, const int* __restrict__ off, int N,
                const float* __restrict__ ddst, const float* __restrict__ bias,
                const float* __restrict__ dsrc, const float* __restrict__ wfold,
                float* __restrict__ tv) {
    int n = blockIdx.x * 8 + (threadIdx.x >> 5);
    if (n >= N) return;
    const int lane = threadIdx.x & 31;
    const int c = lane << 2;      // 4 halfs per lane (8 B)
    int j = off[n];
    const int jend = off[n + 1];
    float4 a0 = make_float4(0.f, 0.f, 0.f, 0.f);
    float4 a1 = make_float4(0.f, 0.f, 0.f, 0.f);
    union H4 { float2 raw; __half2 hh[2]; };
    for (; j + 4 <= jend; j += 4) {
        int i0 = csr[j], i1 = csr[j + 1], i2 = csr[j + 2], i3 = csr[j + 3];
        H4 v0, v1, v2, v3;
        v0.raw = *(const float2*)(T + (size_t)i0 * 128 + c);
        v1.raw = *(const float2*)(T + (size_t)i1 * 128 + c);
        v2.raw = *(const float2*)(T + (size_t)i2 * 128 + c);
        v3.raw = *(const float2*)(T + (size_t)i3 * 128 + c);
        float2 x0 = __half22float2(v0.hh[0]), y0 = __half22float2(v0.hh[1]);
        float2 x1 = __half22float2(v1.hh[0]), y1 = __half22float2(v1.hh[1]);
        float2 x2 = __half22float2(v2.hh[0]), y2 = __half22float2(v2.hh[1]);
        float2 x3 = __half22float2(v3.hh[0]), y3 = __half22float2(v3.hh[1]);
        a0.x += x0.x + x1.x; a0.y += x0.y + x1.y; a0.z += y0.x + y1.x; a0.w += y0.y + y1.y;
        a1.x += x2.x + x3.x; a1.y += x2.y + x3.y; a1.z += y2.x + y3.x; a1.w += y2.y + y3.y;
    }
    for (; j < jend; ++j) {
        int i0 = csr[j];
        H4 v0;
        v0.raw = *(const float2*)(T + (size_t)i0 * 128 + c);
        float2 x0 = __half22float2(v0.hh[0]), y0 = __half22float2(v0.hh[1]);
        a0.x += x0.x; a0.y += x0.y; a0.z += y0.x; a0.w += y0.y;
    }
    float dd = ddst[n];
    float ds = dsrc[n];
    float h0 = lrelu((a0.x + a1.x) * dd + bias[c + 0]);
    float h1 = lrelu((a0.y + a1.y) * dd + bias[c + 1]);
    float h2 = lrelu((a0.z + a1.z) * dd + bias[c + 2]);
    float h3 = lrelu((a0.w + a1.w) * dd + bias[c + 3]);
    if (EPI == 0) {
        union H4 o;
        o.hh[0] = __floats2half2_rn(h0 * ds, h1 * ds);
        o.hh[1] = __floats2half2_rn(h2 * ds, h3 * ds);
        *(float2*)(Hout + (size_t)n * 128 + c) = o.raw;
    } else {
        float s = h0 * wfold[c + 0] + h1 * wfold[c + 1] + h2 * wfold[c + 2] + h3 * wfold[c + 3];
#pragma unroll
        for (int o = 16; o > 0; o >>= 1) s += __shfl_xor(s, o);
        if (lane == 0) tv[n] = s * ds;
    }
}

// ---------------- final: z[n]=sum tv[csr], s=z*ddst+c, per-graph mean bins ----------------
__global__ void k_gather_final(const float* __restrict__ tv, const int* __restrict__ csr,
                               const int* __restrict__ off, const float* __restrict__ ddst,
                               const int* __restrict__ gid, const float* __restrict__ cval,
                               float* __restrict__ gsum, float* __restrict__ gcnt, int N) {
    __shared__ float sb[N_GRAPHS], sc[N_GRAPHS];
    for (int i = threadIdx.x; i < N_GRAPHS; i += blockDim.x) { sb[i] = 0.f; sc[i] = 0.f; }
    __syncthreads();
    int n = blockIdx.x * blockDim.x + threadIdx.x;
    if (n < N) {
        int j = off[n], jend = off[n + 1];
        float z = 0.f;
        for (; j < jend; ++j) z += tv[csr[j]];
        float s = z * ddst[n] + cval[0];
        int g = gid[n];
        atomicAdd(&sb[g], s);
        atomicAdd(&sc[g], 1.f);
    }
    __syncthreads();
    for (int j = threadIdx.x; j < N_GRAPHS; j += blockDim.x) {
        if (sc[j] != 0.f) {
            atomicAdd(&gsum[j], sb[j]);
            atomicAdd(&gcnt[j], sc[j]);
        }
    }
}

__global__ void k_final(const float* __restrict__ gsum, const float* __restrict__ gcnt,
                        float* __restrict__ out) {
    int g = threadIdx.x;
    if (g < N_GRAPHS) out[g] = gsum[g] / fmaxf(gcnt[g], 1.0f);
}

extern "C" void kernel_launch(void* const* d_in, const int* in_sizes, int n_in,
                              void* d_out, int out_size, void* d_ws, size_t ws_size,
                              hipStream_t stream) {
    const float* in_feat = (const float*)d_in[0];
    const float* W1   = (const float*)d_in[1];
    const float* b1   = (const float*)d_in[2];
    const float* W2   = (const float*)d_in[3];
    const float* b2   = (const float*)d_in[4];
    const float* W3   = (const float*)d_in[5];
    const float* b3   = (const float*)d_in[6];
    const float* Wout = (const float*)d_in[7];
    const float* bout = (const float*)d_in[8];
    const int* src = (const int*)d_in[9];
    const int* dst = (const int*)d_in[10];
    const int* gid = (const int*)d_in[11];
    const int N = in_sizes[0] / 128;
    const int E = in_sizes[9];
    float* out = (float*)d_out;

    char* ws = (char*)d_ws;
    size_t woff = 0;
    auto alloc = [&](size_t bytes) {
        void* p = ws + woff;
        woff = (woff + bytes + 255) & ~(size_t)255;
        return p;
    };
    const int nchunks = (N + HCHUNK - 1) / HCHUNK;         // 4 for N=100000
    const int NBINS = nchunks * HCHUNK;
    size_t scr_one = (size_t)NBINS * HBLK;                 // u8: 8.39 MB each
    size_t msg_bytes = (size_t)N * 128 * 2;                // 25.6 MB
    size_t r0_bytes = 2 * scr_one > msg_bytes ? 2 * scr_one : msg_bytes;
    // M0 (fp16 messages) aliases histogram scratch (dead after csrfill2).
    void* region0 = alloc(r0_bytes);
    unsigned char* sdst = (unsigned char*)region0;
    unsigned char* ssrc = (unsigned char*)region0 + scr_one;
    __half* M0          = (__half*)region0;
    __half* M1   = (__half*)alloc(msg_bytes);
    int*   csr   = (int*)alloc((size_t)E * 4);
    int*   off   = (int*)alloc((size_t)(N + 1) * 4);
    int*   partials = (int*)alloc(256 * 4);
    float* dsrc  = (float*)alloc((size_t)N * 4);
    float* ddst  = (float*)alloc((size_t)N * 4);
    float* tv    = (float*)alloc((size_t)N * 4);
    float* wfold = (float*)alloc(128 * 4);
    float* cval  = (float*)alloc(4);
    float* gsum  = (float*)alloc(N_GRAPHS * 4);
    float* gcnt  = (float*)alloc(N_GRAPHS * 4);
    __half* w1T  = (__half*)alloc(16384 * 2);
    __half* w2T  = (__half*)alloc(16384 * 2);
    (void)ws_size; (void)n_in; (void)out_size;

    const int half = nchunks * HBLK;                       // 256

    k_prep<<<3, 256, 0, stream>>>(W1, W2, W3, b3, Wout, bout, w1T, w2T, wfold, cval);

    // degree histograms (u32 LDS bins, u8 scratch out)
    k_hist2<<<2 * half, 512, 0, stream>>>(src, dst, ssrc, sdst, E, half);
    const int nscan = (N + 1023) / 1024;
    k_reduce_scan<<<nscan, 256, 0, stream>>>(ssrc, sdst, dsrc, ddst, off, partials, N);
    // u8 column prefix + scanB (one launch)
    k_colscan_scanB<<<(NBINS + 255) / 256 + 1, 256, 0, stream>>>(sdst, NBINS, partials,
                                                                 nscan, gsum, gcnt);
    k_scanC<<<nscan, 256, 0, stream>>>(off, partials, N, E);
    k_csrfill2<<<half, 512, 0, stream>>>(src, dst, sdst, off, csr, E, N);

    const int gblocks = (N + 127) / 128;
    const int agblocks = (N + 7) / 8;

    // layer 1: M0 = (in_feat * dsrc) @ W1 ; M1 = prenorm(gather(M0), b1)
    k_gemm1<<<gblocks, 512, 0, stream>>>(in_feat, M0, w1T, dsrc, N);
    k_gather_h<0><<<agblocks, 256, 0, stream>>>(M0, M1, csr, off, N, ddst, b1, dsrc, nullptr, nullptr);

    // layer 2: M0 = M1 @ W2 ; M1 = prenorm(gather(M0), b2)
    k_gemm2<<<gblocks, 512, 0, stream>>>(M1, M0, w2T, N);
    k_gather_h<0><<<agblocks, 256, 0, stream>>>(M0, M1, csr, off, N, ddst, b2, dsrc, nullptr, nullptr);

    // layer 3 (conv2 again): M0 = M1 @ W2 ; fused readout gather -> tv
    k_gemm2<<<gblocks, 512, 0, stream>>>(M1, M0, w2T, N);
    k_gather_h<1><<<agblocks, 256, 0, stream>>>(M0, nullptr, csr, off, N, ddst, b2, dsrc, wfold, tv);

    // readout aggregation + per-graph mean
    k_gather_final<<<(N + 255) / 256, 256, 0, stream>>>(tv, csr, off, ddst, gid, cval, gsum, gcnt, N);
    k_final<<<1, 128, 0, stream>>>(gsum, gcnt, out);
}

// Round 14
// 397.126 us; speedup vs baseline: 1.0312x; 1.0312x over previous
//
#include <hip/hip_runtime.h>
#include <hip/hip_fp16.h>
#include <math.h>

#define N_GRAPHS 100
#define HCHUNK 32768
#define HBLK 64

typedef _Float16 f16x8 __attribute__((ext_vector_type(8)));
typedef __attribute__((ext_vector_type(4))) float f32x4;

__device__ __forceinline__ float lrelu(float v) { return v >= 0.f ? v : 0.1f * v; }

// ---------------- prep: wfold/cval + W1/W2 -> transposed+swizzled fp16 ----------------
__global__ void k_prep(const float* __restrict__ W1, const float* __restrict__ W2,
                       const float* __restrict__ W3, const float* __restrict__ b3,
                       const float* __restrict__ Wout, const float* __restrict__ bout,
                       __half* __restrict__ w1T, __half* __restrict__ w2T,
                       float* __restrict__ wfold, float* __restrict__ cval) {
    if (blockIdx.x == 0) {
        int i = threadIdx.x;
        if (i < 128) {
            float s = 0.f;
            for (int j = 0; j < 64; ++j) s += W3[i * 64 + j] * Wout[j];
            wfold[i] = s;
            if (i == 0) {
                float c = bout[0];
                for (int j = 0; j < 64; ++j) c += b3[j] * Wout[j];
                *cval = c;
            }
        }
    } else {
        const float* W = (blockIdx.x == 1) ? W1 : W2;
        __half* wT = (blockIdx.x == 1) ? w1T : w2T;
        for (int i = threadIdx.x; i < 16384; i += 256) {
            int k = i >> 7, col = i & 127;
            wT[col * 128 + (k ^ ((col & 15) << 3))] = __float2half(W[i]);
        }
    }
}

// ---------------- combined src+dst chunked LDS histograms (u32 bins) -> u8 ----------
__global__ __launch_bounds__(512, 1)
void k_hist2(const int* __restrict__ src, const int* __restrict__ dst,
             unsigned char* __restrict__ ssrc, unsigned char* __restrict__ sdst,
             int E, int half) {
    __shared__ int h[HCHUNK];   // 128 KiB
    int id = blockIdx.x;
    const int* keys;
    unsigned char* outbase;
    if (id < half) { keys = dst; outbase = sdst; }
    else           { keys = src; outbase = ssrc; id -= half; }
    const int c = id / HBLK;
    const int b = id % HBLK;
    const int base = c * HCHUNK;
    for (int i = threadIdx.x; i < HCHUNK; i += 512) h[i] = 0;
    __syncthreads();
    for (int i = b * 512 + threadIdx.x; i < E; i += HBLK * 512) {
        unsigned k = (unsigned)(keys[i] - base);
        if (k < HCHUNK) atomicAdd(&h[k], 1);
    }
    __syncthreads();
    unsigned char* outp = outbase + (size_t)(c * HBLK + b) * HCHUNK;
    for (int i = threadIdx.x; i < HCHUNK; i += 512) outp[i] = (unsigned char)h[i];
}

// ---------------- merged: degree reduce (u8) + dinvs + scanA ----------------
__global__ void k_reduce_scan(const unsigned char* __restrict__ ssrc,
                              const unsigned char* __restrict__ sdst,
                              float* __restrict__ dsrc, float* __restrict__ ddst,
                              int* __restrict__ off, int* __restrict__ partials, int N) {
    __shared__ int ts[256];
    const int t = threadIdx.x;
    const int base = blockIdx.x * 1024 + t * 4;
    int v[4];
#pragma unroll
    for (int q = 0; q < 4; ++q) {
        int g = base + q;
        int s2 = 0;
        if (g < N) {
            const int c = g >> 15;
            const int p = g & (HCHUNK - 1);
            const unsigned char* cs = ssrc + (size_t)(c * HBLK) * HCHUNK + p;
            const unsigned char* cd = sdst + (size_t)(c * HBLK) * HCHUNK + p;
            int s1 = 0;
#pragma unroll 8
            for (int b = 0; b < HBLK; ++b) {
                s1 += cs[(size_t)b * HCHUNK];
                s2 += cd[(size_t)b * HCHUNK];
            }
            dsrc[g] = rsqrtf(fmaxf((float)s1, 1.0f));
            ddst[g] = rsqrtf(fmaxf((float)s2, 1.0f));
        }
        v[q] = s2;
    }
    int s = v[0] + v[1] + v[2] + v[3];
    ts[t] = s;
    __syncthreads();
    for (int o = 1; o < 256; o <<= 1) {
        int y = (t >= o) ? ts[t - o] : 0;
        __syncthreads();
        ts[t] += y;
        __syncthreads();
    }
    int excl = ts[t] - s;
    if (base + 0 < N) off[base + 0] = excl;
    if (base + 1 < N) off[base + 1] = excl + v[0];
    if (base + 2 < N) off[base + 2] = excl + v[0] + v[1];
    if (base + 3 < N) off[base + 3] = excl + v[0] + v[1] + v[2];
    if (t == 255) partials[blockIdx.x] = ts[255];
}

// ---------------- merged: u8 column prefix over blocks + scanB (last block) ----------
__global__ void k_colscan_scanB(unsigned char* __restrict__ sdst, int NBINS,
                                int* __restrict__ partials, int nb,
                                float* __restrict__ gsum, float* __restrict__ gcnt) {
    if (blockIdx.x == gridDim.x - 1) {
        __shared__ int ps[256];
        const int t = threadIdx.x;
        if (t < N_GRAPHS) { gsum[t] = 0.f; gcnt[t] = 0.f; }
        int v = (t < nb) ? partials[t] : 0;
        ps[t] = v;
        __syncthreads();
        for (int o = 1; o < 256; o <<= 1) {
            int y = (t >= o) ? ps[t - o] : 0;
            __syncthreads();
            ps[t] += y;
            __syncthreads();
        }
        if (t < nb) partials[t] = ps[t] - v;
        return;
    }
    int g = blockIdx.x * blockDim.x + threadIdx.x;
    if (g >= NBINS) return;
    const int c = g >> 15;
    const int p = g & (HCHUNK - 1);
    unsigned char* col = sdst + (size_t)(c * HBLK) * HCHUNK + p;
    int run = 0;
    for (int b = 0; b < HBLK; ++b) {
        unsigned char* q = col + (size_t)b * HCHUNK;
        int t = *q;
        *q = (unsigned char)run;
        run += t;
    }
}

__global__ void k_scanC(int* __restrict__ off, const int* __restrict__ partials, int N, int E) {
    const int t = threadIdx.x;
    const int base = blockIdx.x * 1024 + t * 4;
    const int add = partials[blockIdx.x];
#pragma unroll
    for (int q = 0; q < 4; ++q) {
        int idx = base + q;
        if (idx < N) off[idx] += add;
    }
    if (blockIdx.x == 0 && t == 0) off[N] = E;
}

// ---------------- CSR fill via LDS cursors (cursor = off + u8 prefix) ----------------
__global__ __launch_bounds__(512, 1)
void k_csrfill2(const int* __restrict__ src, const int* __restrict__ dst,
                const unsigned char* __restrict__ pref, const int* __restrict__ off,
                int* __restrict__ csr, int E, int N) {
    __shared__ int cur[HCHUNK];   // 128 KiB
    const int c = blockIdx.x / HBLK;
    const int b = blockIdx.x % HBLK;
    const int base = c * HCHUNK;
    const unsigned char* my = pref + (size_t)(c * HBLK + b) * HCHUNK;
    for (int i = threadIdx.x; i < HCHUNK; i += 512) {
        int g = base + i;
        cur[i] = ((g < N) ? off[g] : 0) + (int)my[i];
    }
    __syncthreads();
    for (int i = b * 512 + threadIdx.x; i < E; i += HBLK * 512) {
        unsigned k = (unsigned)(dst[i] - base);
        if (k < HCHUNK) {
            int p = atomicAdd(&cur[k], 1);
            csr[p] = src[i];
        }
    }
}

// ---------------- fp16 MFMA GEMM:  M = X @ W  (Ws staged in LDS) ----------------
// PRE==2: X fp32, prenorm x*dinv_src (layer 1).  PRE==0: X fp16, pure GEMM.
template <int PRE>
__global__ __launch_bounds__(512, 2)
void k_gemm_mfma(const void* __restrict__ Xv, __half* __restrict__ Y,
                 const __half* __restrict__ wT, const float* __restrict__ dinv_src,
                 int N) {
    __shared__ __half Xs[128 * 128];  // 32 KiB
    __shared__ __half Ws[128 * 128];  // 32 KiB
    const int t = threadIdx.x;
    const int r0 = blockIdx.x * 128;

    for (int i = t; i < 2048; i += 512) ((float4*)Ws)[i] = ((const float4*)wT)[i];

    if (PRE == 2) {
        const float* X = (const float*)Xv;
        for (int i = t; i < 4096; i += 512) {
            int row = i >> 5;
            int g4 = (i & 31) << 2;
            int grow = r0 + row;
            float4 v = make_float4(0.f, 0.f, 0.f, 0.f);
            if (grow < N) {
                v = ((const float4*)(X + (size_t)grow * 128))[i & 31];
                float ds = dinv_src[grow];
                v.x *= ds; v.y *= ds; v.z *= ds; v.w *= ds;
            }
            union { float2 f; __half2 h[2]; } pk;
            pk.h[0] = __floats2half2_rn(v.x, v.y);
            pk.h[1] = __floats2half2_rn(v.z, v.w);
            *(float2*)&Xs[row * 128 + (g4 ^ ((row & 15) << 3))] = pk.f;
        }
    } else {
        const __half* X = (const __half*)Xv;
        for (int i = t; i < 2048; i += 512) {
            int row = i >> 4;
            int g8 = (i & 15) << 3;
            int grow = r0 + row;
            uint4 v = make_uint4(0u, 0u, 0u, 0u);
            if (grow < N) v = ((const uint4*)(X + (size_t)grow * 128))[i & 15];
            *(uint4*)&Xs[row * 128 + (g8 ^ ((row & 15) << 3))] = v;
        }
    }
    __syncthreads();

    const int w = t >> 6;
    const int wm = w & 3;
    const int wn = w >> 2;
    const int lane = t & 63;
    const int lr = lane & 15;
    const int lg = lane >> 4;

    f32x4 acc[2][4];
#pragma unroll
    for (int mi = 0; mi < 2; ++mi)
#pragma unroll
        for (int ni = 0; ni < 4; ++ni) acc[mi][ni] = (f32x4){0.f, 0.f, 0.f, 0.f};

#pragma unroll
    for (int ks = 0; ks < 4; ++ks) {
        const int k0 = 32 * ks + 4 * lg;
        union F { float2 f[2]; f16x8 v; };
        F a[2];
#pragma unroll
        for (int mi = 0; mi < 2; ++mi) {
            int row = 32 * wm + 16 * mi + lr;
            int sw = (row & 15) << 3;
            a[mi].f[0] = *(const float2*)&Xs[row * 128 + (k0 ^ sw)];
            a[mi].f[1] = *(const float2*)&Xs[row * 128 + ((k0 + 16) ^ sw)];
        }
#pragma unroll
        for (int ni = 0; ni < 4; ++ni) {
            int colv = 64 * wn + 16 * ni + lr;
            int sw = (colv & 15) << 3;
            F b;
            b.f[0] = *(const float2*)&Ws[colv * 128 + (k0 ^ sw)];
            b.f[1] = *(const float2*)&Ws[colv * 128 + ((k0 + 16) ^ sw)];
#pragma unroll
            for (int mi = 0; mi < 2; ++mi)
                acc[mi][ni] = __builtin_amdgcn_mfma_f32_16x16x32_f16(a[mi].v, b.v, acc[mi][ni], 0, 0, 0);
        }
    }

    __syncthreads();
#pragma unroll
    for (int mi = 0; mi < 2; ++mi)
#pragma unroll
        for (int r = 0; r < 4; ++r) {
            int row = 32 * wm + 16 * mi + 4 * lg + r;
#pragma unroll
            for (int ni = 0; ni < 4; ++ni)
                Xs[row * 128 + 64 * wn + 16 * ni + lr] = __float2half(acc[mi][ni][r]);
        }
    __syncthreads();
    for (int i = t; i < 2048; i += 512) {
        int row = i >> 4;
        int grow = r0 + row;
        if (grow < N) {
            int col8 = (i & 15) << 3;
            *(uint4*)(Y + (size_t)grow * 128 + col8) = *(const uint4*)&Xs[row * 128 + col8];
        }
    }
}

// ---------------- CSR gather (fp16 msgs), half-wave per node, 4-edge unroll ----------
// EPI==0: H[n] = fp16( lrelu(agg*ddst + bias) * dsrc )
// EPI==1: tv[n] = dsrc * ( lrelu(agg*ddst + bias) . wfold )
template <int EPI>
__global__ __launch_bounds__(256)
void k_gather_h(const __half* __restrict__ T, __half* __restrict__ Hout,
                const int* __restrict__ csr, const int* __restrict__ off, int N,
                const float* __restrict__ ddst, const float* __restrict__ bias,
                const float* __restrict__ dsrc, const float* __restrict__ wfold,
                float* __restrict__ tv) {
    int n = blockIdx.x * 8 + (threadIdx.x >> 5);
    if (n >= N) return;
    const int lane = threadIdx.x & 31;
    const int c = lane << 2;      // 4 halfs per lane (8 B)
    int j = off[n];
    const int jend = off[n + 1];
    float4 a0 = make_float4(0.f, 0.f, 0.f, 0.f);
    float4 a1 = make_float4(0.f, 0.f, 0.f, 0.f);
    union H4 { float2 raw; __half2 hh[2]; };
    for (; j + 4 <= jend; j += 4) {
        int i0 = csr[j], i1 = csr[j + 1], i2 = csr[j + 2], i3 = csr[j + 3];
        H4 v0, v1, v2, v3;
        v0.raw = *(const float2*)(T + (size_t)i0 * 128 + c);
        v1.raw = *(const float2*)(T + (size_t)i1 * 128 + c);
        v2.raw = *(const float2*)(T + (size_t)i2 * 128 + c);
        v3.raw = *(const float2*)(T + (size_t)i3 * 128 + c);
        float2 x0 = __half22float2(v0.hh[0]), y0 = __half22float2(v0.hh[1]);
        float2 x1 = __half22float2(v1.hh[0]), y1 = __half22float2(v1.hh[1]);
        float2 x2 = __half22float2(v2.hh[0]), y2 = __half22float2(v2.hh[1]);
        float2 x3 = __half22float2(v3.hh[0]), y3 = __half22float2(v3.hh[1]);
        a0.x += x0.x + x1.x; a0.y += x0.y + x1.y; a0.z += y0.x + y1.x; a0.w += y0.y + y1.y;
        a1.x += x2.x + x3.x; a1.y += x2.y + x3.y; a1.z += y2.x + y3.x; a1.w += y2.y + y3.y;
    }
    for (; j < jend; ++j) {
        int i0 = csr[j];
        H4 v0;
        v0.raw = *(const float2*)(T + (size_t)i0 * 128 + c);
        float2 x0 = __half22float2(v0.hh[0]), y0 = __half22float2(v0.hh[1]);
        a0.x += x0.x; a0.y += x0.y; a0.z += y0.x; a0.w += y0.y;
    }
    float dd = ddst[n];
    float ds = dsrc[n];
    float h0 = lrelu((a0.x + a1.x) * dd + bias[c + 0]);
    float h1 = lrelu((a0.y + a1.y) * dd + bias[c + 1]);
    float h2 = lrelu((a0.z + a1.z) * dd + bias[c + 2]);
    float h3 = lrelu((a0.w + a1.w) * dd + bias[c + 3]);
    if (EPI == 0) {
        union H4 o;
        o.hh[0] = __floats2half2_rn(h0 * ds, h1 * ds);
        o.hh[1] = __floats2half2_rn(h2 * ds, h3 * ds);
        *(float2*)(Hout + (size_t)n * 128 + c) = o.raw;
    } else {
        float s = h0 * wfold[c + 0] + h1 * wfold[c + 1] + h2 * wfold[c + 2] + h3 * wfold[c + 3];
#pragma unroll
        for (int o = 16; o > 0; o >>= 1) s += __shfl_xor(s, o);
        if (lane == 0) tv[n] = s * ds;
    }
}

// ---------------- final: z[n]=sum tv[csr], s=z*ddst+c, per-graph mean bins ----------------
__global__ void k_gather_final(const float* __restrict__ tv, const int* __restrict__ csr,
                               const int* __restrict__ off, const float* __restrict__ ddst,
                               const int* __restrict__ gid, const float* __restrict__ cval,
                               float* __restrict__ gsum, float* __restrict__ gcnt, int N) {
    __shared__ float sb[N_GRAPHS], sc[N_GRAPHS];
    for (int i = threadIdx.x; i < N_GRAPHS; i += blockDim.x) { sb[i] = 0.f; sc[i] = 0.f; }
    __syncthreads();
    int n = blockIdx.x * blockDim.x + threadIdx.x;
    if (n < N) {
        int j = off[n], jend = off[n + 1];
        float z = 0.f;
        for (; j < jend; ++j) z += tv[csr[j]];
        float s = z * ddst[n] + cval[0];
        int g = gid[n];
        atomicAdd(&sb[g], s);
        atomicAdd(&sc[g], 1.f);
    }
    __syncthreads();
    for (int j = threadIdx.x; j < N_GRAPHS; j += blockDim.x) {
        if (sc[j] != 0.f) {
            atomicAdd(&gsum[j], sb[j]);
            atomicAdd(&gcnt[j], sc[j]);
        }
    }
}

__global__ void k_final(const float* __restrict__ gsum, const float* __restrict__ gcnt,
                        float* __restrict__ out) {
    int g = threadIdx.x;
    if (g < N_GRAPHS) out[g] = gsum[g] / fmaxf(gcnt[g], 1.0f);
}

extern "C" void kernel_launch(void* const* d_in, const int* in_sizes, int n_in,
                              void* d_out, int out_size, void* d_ws, size_t ws_size,
                              hipStream_t stream) {
    const float* in_feat = (const float*)d_in[0];
    const float* W1   = (const float*)d_in[1];
    const float* b1   = (const float*)d_in[2];
    const float* W2   = (const float*)d_in[3];
    const float* b2   = (const float*)d_in[4];
    const float* W3   = (const float*)d_in[5];
    const float* b3   = (const float*)d_in[6];
    const float* Wout = (const float*)d_in[7];
    const float* bout = (const float*)d_in[8];
    const int* src = (const int*)d_in[9];
    const int* dst = (const int*)d_in[10];
    const int* gid = (const int*)d_in[11];
    const int N = in_sizes[0] / 128;
    const int E = in_sizes[9];
    float* out = (float*)d_out;

    char* ws = (char*)d_ws;
    size_t woff = 0;
    auto alloc = [&](size_t bytes) {
        void* p = ws + woff;
        woff = (woff + bytes + 255) & ~(size_t)255;
        return p;
    };
    const int nchunks = (N + HCHUNK - 1) / HCHUNK;         // 4 for N=100000
    const int NBINS = nchunks * HCHUNK;
    size_t scr_one = (size_t)NBINS * HBLK;                 // u8: 8.39 MB each
    size_t msg_bytes = (size_t)N * 128 * 2;                // 25.6 MB
    size_t r0_bytes = 2 * scr_one > msg_bytes ? 2 * scr_one : msg_bytes;
    // M0 (fp16 messages) aliases histogram scratch (dead after csrfill2).
    void* region0 = alloc(r0_bytes);
    unsigned char* sdst = (unsigned char*)region0;
    unsigned char* ssrc = (unsigned char*)region0 + scr_one;
    __half* M0          = (__half*)region0;
    __half* M1   = (__half*)alloc(msg_bytes);
    int*   csr   = (int*)alloc((size_t)E * 4);
    int*   off   = (int*)alloc((size_t)(N + 1) * 4);
    int*   partials = (int*)alloc(256 * 4);
    float* dsrc  = (float*)alloc((size_t)N * 4);
    float* ddst  = (float*)alloc((size_t)N * 4);
    float* tv    = (float*)alloc((size_t)N * 4);
    float* wfold = (float*)alloc(128 * 4);
    float* cval  = (float*)alloc(4);
    float* gsum  = (float*)alloc(N_GRAPHS * 4);
    float* gcnt  = (float*)alloc(N_GRAPHS * 4);
    __half* w1T  = (__half*)alloc(16384 * 2);
    __half* w2T  = (__half*)alloc(16384 * 2);
    (void)ws_size; (void)n_in; (void)out_size;

    const int half = nchunks * HBLK;                       // 256

    k_prep<<<3, 256, 0, stream>>>(W1, W2, W3, b3, Wout, bout, w1T, w2T, wfold, cval);

    // degree histograms (u32 LDS bins, u8 scratch out)
    k_hist2<<<2 * half, 512, 0, stream>>>(src, dst, ssrc, sdst, E, half);
    const int nscan = (N + 1023) / 1024;
    k_reduce_scan<<<nscan, 256, 0, stream>>>(ssrc, sdst, dsrc, ddst, off, partials, N);
    // u8 column prefix + scanB (one launch)
    k_colscan_scanB<<<(NBINS + 255) / 256 + 1, 256, 0, stream>>>(sdst, NBINS, partials,
                                                                 nscan, gsum, gcnt);
    k_scanC<<<nscan, 256, 0, stream>>>(off, partials, N, E);
    k_csrfill2<<<half, 512, 0, stream>>>(src, dst, sdst, off, csr, E, N);

    const int gblocks = (N + 127) / 128;
    const int agblocks = (N + 7) / 8;

    // layer 1: M0 = (in_feat * dsrc) @ W1 ; M1 = prenorm(gather(M0), b1)
    k_gemm_mfma<2><<<gblocks, 512, 0, stream>>>(in_feat, M0, w1T, dsrc, N);
    k_gather_h<0><<<agblocks, 256, 0, stream>>>(M0, M1, csr, off, N, ddst, b1, dsrc, nullptr, nullptr);

    // layer 2: M0 = M1 @ W2 ; M1 = prenorm(gather(M0), b2)
    k_gemm_mfma<0><<<gblocks, 512, 0, stream>>>(M1, M0, w2T, nullptr, N);
    k_gather_h<0><<<agblocks, 256, 0, stream>>>(M0, M1, csr, off, N, ddst, b2, dsrc, nullptr, nullptr);

    // layer 3 (conv2 again): M0 = M1 @ W2 ; fused readout gather -> tv
    k_gemm_mfma<0><<<gblocks, 512, 0, stream>>>(M1, M0, w2T, nullptr, N);
    k_gather_h<1><<<agblocks, 256, 0, stream>>>(M0, nullptr, csr, off, N, ddst, b2, dsrc, wfold, tv);

    // readout aggregation + per-graph mean
    k_gather_final<<<(N + 255) / 256, 256, 0, stream>>>(tv, csr, off, ddst, gid, cval, gsum, gcnt, N);
    k_final<<<1, 128, 0, stream>>>(gsum, gcnt, out);
}

// Round 15
// 379.011 us; speedup vs baseline: 1.0805x; 1.0478x over previous
//
#include <hip/hip_runtime.h>
#include <hip/hip_fp16.h>
#include <math.h>

#define N_GRAPHS 100
#define HCHUNK 32768
#define HBLK 64

typedef _Float16 f16x8 __attribute__((ext_vector_type(8)));
typedef __attribute__((ext_vector_type(4))) float f32x4;

__device__ __forceinline__ float lrelu(float v) { return v >= 0.f ? v : 0.1f * v; }

// ---------------- prep: wfold/cval + W1/W2 -> transposed+swizzled fp16 ----------------
__global__ void k_prep(const float* __restrict__ W1, const float* __restrict__ W2,
                       const float* __restrict__ W3, const float* __restrict__ b3,
                       const float* __restrict__ Wout, const float* __restrict__ bout,
                       __half* __restrict__ w1T, __half* __restrict__ w2T,
                       float* __restrict__ wfold, float* __restrict__ cval) {
    if (blockIdx.x == 0) {
        int i = threadIdx.x;
        if (i < 128) {
            float s = 0.f;
            for (int j = 0; j < 64; ++j) s += W3[i * 64 + j] * Wout[j];
            wfold[i] = s;
            if (i == 0) {
                float c = bout[0];
                for (int j = 0; j < 64; ++j) c += b3[j] * Wout[j];
                *cval = c;
            }
        }
    } else {
        const float* W = (blockIdx.x == 1) ? W1 : W2;
        __half* wT = (blockIdx.x == 1) ? w1T : w2T;
        for (int i = threadIdx.x; i < 16384; i += 256) {
            int k = i >> 7, col = i & 127;
            wT[col * 128 + (k ^ ((col & 15) << 3))] = __float2half(W[i]);
        }
    }
}

// ---------------- combined src+dst chunked LDS histograms -> u16 per-block counts ----
__global__ __launch_bounds__(512, 1)
void k_hist2(const int* __restrict__ src, const int* __restrict__ dst,
             unsigned short* __restrict__ ssrc, unsigned short* __restrict__ sdst,
             int E, int half) {
    __shared__ int h[HCHUNK];   // 128 KiB
    int id = blockIdx.x;
    const int* keys;
    unsigned short* outbase;
    if (id < half) { keys = dst; outbase = sdst; }
    else           { keys = src; outbase = ssrc; id -= half; }
    const int c = id / HBLK;
    const int b = id % HBLK;
    const int base = c * HCHUNK;
    for (int i = threadIdx.x; i < HCHUNK; i += 512) h[i] = 0;
    __syncthreads();
    for (int i = b * 512 + threadIdx.x; i < E; i += HBLK * 512) {
        unsigned k = (unsigned)(keys[i] - base);
        if (k < HCHUNK) atomicAdd(&h[k], 1);
    }
    __syncthreads();
    unsigned short* outp = outbase + (size_t)(c * HBLK + b) * HCHUNK;
    for (int i = threadIdx.x; i < HCHUNK; i += 512) outp[i] = (unsigned short)h[i];
}

// ---------------- combined reduce: dsrc, degd, ddst ----------------
__global__ void k_reduce2(const unsigned short* __restrict__ ssrc,
                          const unsigned short* __restrict__ sdst,
                          float* __restrict__ dsrc, int* __restrict__ degd,
                          float* __restrict__ ddst, int N) {
    int g = blockIdx.x * blockDim.x + threadIdx.x;
    if (g >= N) return;
    const int c = g >> 15;
    const int p = g & (HCHUNK - 1);
    const unsigned short* cs = ssrc + (size_t)(c * HBLK) * HCHUNK + p;
    const unsigned short* cd = sdst + (size_t)(c * HBLK) * HCHUNK + p;
    int s1 = 0, s2 = 0;
#pragma unroll 8
    for (int b = 0; b < HBLK; ++b) {
        s1 += cs[(size_t)b * HCHUNK];
        s2 += cd[(size_t)b * HCHUNK];
    }
    dsrc[g] = rsqrtf(fmaxf((float)s1, 1.0f));
    degd[g] = s2;
    ddst[g] = rsqrtf(fmaxf((float)s2, 1.0f));
}

// ---------------- exclusive scan over degd -> off (3-kernel) ----------------
__global__ void k_scanA(const int* __restrict__ deg, int* __restrict__ off,
                        int* __restrict__ partials, int N) {
    __shared__ int ts[256];
    const int t = threadIdx.x;
    const int base = blockIdx.x * 1024 + t * 4;
    int v0 = (base + 0 < N) ? deg[base + 0] : 0;
    int v1 = (base + 1 < N) ? deg[base + 1] : 0;
    int v2 = (base + 2 < N) ? deg[base + 2] : 0;
    int v3 = (base + 3 < N) ? deg[base + 3] : 0;
    int s = v0 + v1 + v2 + v3;
    ts[t] = s;
    __syncthreads();
    for (int o = 1; o < 256; o <<= 1) {
        int y = (t >= o) ? ts[t - o] : 0;
        __syncthreads();
        ts[t] += y;
        __syncthreads();
    }
    int excl = ts[t] - s;
    if (base + 0 < N) off[base + 0] = excl;
    if (base + 1 < N) off[base + 1] = excl + v0;
    if (base + 2 < N) off[base + 2] = excl + v0 + v1;
    if (base + 3 < N) off[base + 3] = excl + v0 + v1 + v2;
    if (t == 255) partials[blockIdx.x] = ts[255];
}

// scanB also zero-inits gsum/gcnt (replaces two memsets)
__global__ void k_scanB(int* __restrict__ partials, int nb,
                        float* __restrict__ gsum, float* __restrict__ gcnt) {
    __shared__ int ps[256];
    const int t = threadIdx.x;
    if (t < N_GRAPHS) { gsum[t] = 0.f; gcnt[t] = 0.f; }
    int v = (t < nb) ? partials[t] : 0;
    ps[t] = v;
    __syncthreads();
    for (int o = 1; o < 256; o <<= 1) {
        int y = (t >= o) ? ps[t - o] : 0;
        __syncthreads();
        ps[t] += y;
        __syncthreads();
    }
    if (t < nb) partials[t] = ps[t] - v;
}

__global__ void k_scanC(int* __restrict__ off, const int* __restrict__ partials, int N, int E) {
    const int t = threadIdx.x;
    const int base = blockIdx.x * 1024 + t * 4;
    const int add = partials[blockIdx.x];
#pragma unroll
    for (int q = 0; q < 4; ++q) {
        int idx = base + q;
        if (idx < N) off[idx] += add;
    }
    if (blockIdx.x == 0 && t == 0) off[N] = E;
}

// ---------------- in-place u16 column prefix over blocks ----------------
__global__ void k_colscan16(unsigned short* __restrict__ sdst, int NBINS) {
    int g = blockIdx.x * blockDim.x + threadIdx.x;
    if (g >= NBINS) return;
    const int c = g >> 15;
    const int p = g & (HCHUNK - 1);
    unsigned short* col = sdst + (size_t)(c * HBLK) * HCHUNK + p;
    int run = 0;
    for (int b = 0; b < HBLK; ++b) {
        unsigned short* q = col + (size_t)b * HCHUNK;
        int t = *q;
        *q = (unsigned short)run;
        run += t;
    }
}

// ---------------- CSR fill via LDS cursors (cursor = off + u16 prefix) ----------------
__global__ __launch_bounds__(512, 1)
void k_csrfill2(const int* __restrict__ src, const int* __restrict__ dst,
                const unsigned short* __restrict__ pref, const int* __restrict__ off,
                int* __restrict__ csr, int E, int N) {
    __shared__ int cur[HCHUNK];   // 128 KiB
    const int c = blockIdx.x / HBLK;
    const int b = blockIdx.x % HBLK;
    const int base = c * HCHUNK;
    const unsigned short* my = pref + (size_t)(c * HBLK + b) * HCHUNK;
    for (int i = threadIdx.x; i < HCHUNK; i += 512) {
        int g = base + i;
        cur[i] = ((g < N) ? off[g] : 0) + (int)my[i];
    }
    __syncthreads();
    for (int i = b * 512 + threadIdx.x; i < E; i += HBLK * 512) {
        unsigned k = (unsigned)(dst[i] - base);
        if (k < HCHUNK) {
            int p = atomicAdd(&cur[k], 1);
            csr[p] = src[i];
        }
    }
}

// ---------------- fp16 MFMA GEMM:  M = X @ W ----------------
// PRE==2: X fp32, prenorm x*dinv_src (layer 1).  PRE==0: X fp16, pure GEMM.
template <int PRE>
__global__ __launch_bounds__(512, 2)
void k_gemm_mfma(const void* __restrict__ Xv, __half* __restrict__ Y,
                 const __half* __restrict__ wT, const float* __restrict__ dinv_src,
                 int N) {
    __shared__ __half Xs[128 * 128];  // 32 KiB
    __shared__ __half Ws[128 * 128];  // 32 KiB
    const int t = threadIdx.x;
    const int r0 = blockIdx.x * 128;

    for (int i = t; i < 2048; i += 512) ((float4*)Ws)[i] = ((const float4*)wT)[i];

    if (PRE == 2) {
        const float* X = (const float*)Xv;
        for (int i = t; i < 4096; i += 512) {
            int row = i >> 5;
            int g4 = (i & 31) << 2;
            int grow = r0 + row;
            float4 v = make_float4(0.f, 0.f, 0.f, 0.f);
            if (grow < N) {
                v = ((const float4*)(X + (size_t)grow * 128))[i & 31];
                float ds = dinv_src[grow];
                v.x *= ds; v.y *= ds; v.z *= ds; v.w *= ds;
            }
            union { float2 f; __half2 h[2]; } pk;
            pk.h[0] = __floats2half2_rn(v.x, v.y);
            pk.h[1] = __floats2half2_rn(v.z, v.w);
            *(float2*)&Xs[row * 128 + (g4 ^ ((row & 15) << 3))] = pk.f;
        }
    } else {
        const __half* X = (const __half*)Xv;
        for (int i = t; i < 2048; i += 512) {
            int row = i >> 4;
            int g8 = (i & 15) << 3;
            int grow = r0 + row;
            uint4 v = make_uint4(0u, 0u, 0u, 0u);
            if (grow < N) v = ((const uint4*)(X + (size_t)grow * 128))[i & 15];
            *(uint4*)&Xs[row * 128 + (g8 ^ ((row & 15) << 3))] = v;
        }
    }
    __syncthreads();

    const int w = t >> 6;
    const int wm = w & 3;
    const int wn = w >> 2;
    const int lane = t & 63;
    const int lr = lane & 15;
    const int lg = lane >> 4;

    f32x4 acc[2][4];
#pragma unroll
    for (int mi = 0; mi < 2; ++mi)
#pragma unroll
        for (int ni = 0; ni < 4; ++ni) acc[mi][ni] = (f32x4){0.f, 0.f, 0.f, 0.f};

#pragma unroll
    for (int ks = 0; ks < 4; ++ks) {
        const int k0 = 32 * ks + 4 * lg;
        union F { float2 f[2]; f16x8 v; };
        F a[2];
#pragma unroll
        for (int mi = 0; mi < 2; ++mi) {
            int row = 32 * wm + 16 * mi + lr;
            int sw = (row & 15) << 3;
            a[mi].f[0] = *(const float2*)&Xs[row * 128 + (k0 ^ sw)];
            a[mi].f[1] = *(const float2*)&Xs[row * 128 + ((k0 + 16) ^ sw)];
        }
#pragma unroll
        for (int ni = 0; ni < 4; ++ni) {
            int colv = 64 * wn + 16 * ni + lr;
            int sw = (colv & 15) << 3;
            F b;
            b.f[0] = *(const float2*)&Ws[colv * 128 + (k0 ^ sw)];
            b.f[1] = *(const float2*)&Ws[colv * 128 + ((k0 + 16) ^ sw)];
#pragma unroll
            for (int mi = 0; mi < 2; ++mi)
                acc[mi][ni] = __builtin_amdgcn_mfma_f32_16x16x32_f16(a[mi].v, b.v, acc[mi][ni], 0, 0, 0);
        }
    }

    __syncthreads();
#pragma unroll
    for (int mi = 0; mi < 2; ++mi)
#pragma unroll
        for (int r = 0; r < 4; ++r) {
            int row = 32 * wm + 16 * mi + 4 * lg + r;
#pragma unroll
            for (int ni = 0; ni < 4; ++ni)
                Xs[row * 128 + 64 * wn + 16 * ni + lr] = __float2half(acc[mi][ni][r]);
        }
    __syncthreads();
    for (int i = t; i < 2048; i += 512) {
        int row = i >> 4;
        int grow = r0 + row;
        if (grow < N) {
            int col8 = (i & 15) << 3;
            *(uint4*)(Y + (size_t)grow * 128 + col8) = *(const uint4*)&Xs[row * 128 + col8];
        }
    }
}

// ---------------- CSR gather (fp16 msgs), half-wave per node, 4-edge unroll ----------
// EPI==0: H[n] = fp16( lrelu(agg*ddst + bias) * dsrc )
// EPI==1: tv[n] = dsrc * ( lrelu(agg*ddst + bias) . wfold )
template <int EPI>
__global__ __launch_bounds__(256)
void k_gather_h(const __half* __restrict__ T, __half* __restrict__ Hout,
                const int* __restrict__ csr, const int* __restrict__ off, int N,
                const float* __restrict__ ddst, const float* __restrict__ bias,
                const float* __restrict__ dsrc, const float* __restrict__ wfold,
                float* __restrict__ tv) {
    int n = blockIdx.x * 8 + (threadIdx.x >> 5);
    if (n >= N) return;
    const int lane = threadIdx.x & 31;
    const int c = lane << 2;      // 4 halfs per lane (8 B)
    int j = off[n];
    const int jend = off[n + 1];
    float4 a0 = make_float4(0.f, 0.f, 0.f, 0.f);
    float4 a1 = make_float4(0.f, 0.f, 0.f, 0.f);
    union H4 { float2 raw; __half2 hh[2]; };
    for (; j + 4 <= jend; j += 4) {
        int i0 = csr[j], i1 = csr[j + 1], i2 = csr[j + 2], i3 = csr[j + 3];
        H4 v0, v1, v2, v3;
        v0.raw = *(const float2*)(T + (size_t)i0 * 128 + c);
        v1.raw = *(const float2*)(T + (size_t)i1 * 128 + c);
        v2.raw = *(const float2*)(T + (size_t)i2 * 128 + c);
        v3.raw = *(const float2*)(T + (size_t)i3 * 128 + c);
        float2 x0 = __half22float2(v0.hh[0]), y0 = __half22float2(v0.hh[1]);
        float2 x1 = __half22float2(v1.hh[0]), y1 = __half22float2(v1.hh[1]);
        float2 x2 = __half22float2(v2.hh[0]), y2 = __half22float2(v2.hh[1]);
        float2 x3 = __half22float2(v3.hh[0]), y3 = __half22float2(v3.hh[1]);
        a0.x += x0.x + x1.x; a0.y += x0.y + x1.y; a0.z += y0.x + y1.x; a0.w += y0.y + y1.y;
        a1.x += x2.x + x3.x; a1.y += x2.y + x3.y; a1.z += y2.x + y3.x; a1.w += y2.y + y3.y;
    }
    for (; j < jend; ++j) {
        int i0 = csr[j];
        H4 v0;
        v0.raw = *(const float2*)(T + (size_t)i0 * 128 + c);
        float2 x0 = __half22float2(v0.hh[0]), y0 = __half22float2(v0.hh[1]);
        a0.x += x0.x; a0.y += x0.y; a0.z += y0.x; a0.w += y0.y;
    }
    float dd = ddst[n];
    float ds = dsrc[n];
    float h0 = lrelu((a0.x + a1.x) * dd + bias[c + 0]);
    float h1 = lrelu((a0.y + a1.y) * dd + bias[c + 1]);
    float h2 = lrelu((a0.z + a1.z) * dd + bias[c + 2]);
    float h3 = lrelu((a0.w + a1.w) * dd + bias[c + 3]);
    if (EPI == 0) {
        union H4 o;
        o.hh[0] = __floats2half2_rn(h0 * ds, h1 * ds);
        o.hh[1] = __floats2half2_rn(h2 * ds, h3 * ds);
        *(float2*)(Hout + (size_t)n * 128 + c) = o.raw;
    } else {
        float s = h0 * wfold[c + 0] + h1 * wfold[c + 1] + h2 * wfold[c + 2] + h3 * wfold[c + 3];
#pragma unroll
        for (int o = 16; o > 0; o >>= 1) s += __shfl_xor(s, o);
        if (lane == 0) tv[n] = s * ds;
    }
}

// ---------------- final: z[n]=sum tv[csr], s=z*ddst+c, per-graph mean bins ----------------
__global__ void k_gather_final(const float* __restrict__ tv, const int* __restrict__ csr,
                               const int* __restrict__ off, const float* __restrict__ ddst,
                               const int* __restrict__ gid, const float* __restrict__ cval,
                               float* __restrict__ gsum, float* __restrict__ gcnt, int N) {
    __shared__ float sb[N_GRAPHS], sc[N_GRAPHS];
    for (int i = threadIdx.x; i < N_GRAPHS; i += blockDim.x) { sb[i] = 0.f; sc[i] = 0.f; }
    __syncthreads();
    int n = blockIdx.x * blockDim.x + threadIdx.x;
    if (n < N) {
        int j = off[n], jend = off[n + 1];
        float z = 0.f;
        for (; j < jend; ++j) z += tv[csr[j]];
        float s = z * ddst[n] + cval[0];
        int g = gid[n];
        atomicAdd(&sb[g], s);
        atomicAdd(&sc[g], 1.f);
    }
    __syncthreads();
    for (int j = threadIdx.x; j < N_GRAPHS; j += blockDim.x) {
        if (sc[j] != 0.f) {
            atomicAdd(&gsum[j], sb[j]);
            atomicAdd(&gcnt[j], sc[j]);
        }
    }
}

__global__ void k_final(const float* __restrict__ gsum, const float* __restrict__ gcnt,
                        float* __restrict__ out) {
    int g = threadIdx.x;
    if (g < N_GRAPHS) out[g] = gsum[g] / fmaxf(gcnt[g], 1.0f);
}

extern "C" void kernel_launch(void* const* d_in, const int* in_sizes, int n_in,
                              void* d_out, int out_size, void* d_ws, size_t ws_size,
                              hipStream_t stream) {
    const float* in_feat = (const float*)d_in[0];
    const float* W1   = (const float*)d_in[1];
    const float* b1   = (const float*)d_in[2];
    const float* W2   = (const float*)d_in[3];
    const float* b2   = (const float*)d_in[4];
    const float* W3   = (const float*)d_in[5];
    const float* b3   = (const float*)d_in[6];
    const float* Wout = (const float*)d_in[7];
    const float* bout = (const float*)d_in[8];
    const int* src = (const int*)d_in[9];
    const int* dst = (const int*)d_in[10];
    const int* gid = (const int*)d_in[11];
    const int N = in_sizes[0] / 128;
    const int E = in_sizes[9];
    float* out = (float*)d_out;

    char* ws = (char*)d_ws;
    size_t woff = 0;
    auto alloc = [&](size_t bytes) {
        void* p = ws + woff;
        woff = (woff + bytes + 255) & ~(size_t)255;
        return p;
    };
    const int nchunks = (N + HCHUNK - 1) / HCHUNK;         // 4 for N=100000
    const int NBINS = nchunks * HCHUNK;
    size_t scr_one = (size_t)NBINS * HBLK * 2;             // u16: 16.78 MB each
    size_t msg_bytes = (size_t)N * 128 * 2;                // 25.6 MB
    size_t r0_bytes = 2 * scr_one > msg_bytes ? 2 * scr_one : msg_bytes;
    // M0 (fp16 messages) aliases histogram scratch (dead after csrfill2).
    void* region0 = alloc(r0_bytes);
    unsigned short* sdst = (unsigned short*)region0;
    unsigned short* ssrc = (unsigned short*)((char*)region0 + scr_one);
    __half* M0           = (__half*)region0;
    __half* M1   = (__half*)alloc(msg_bytes);
    int*   csr   = (int*)alloc((size_t)E * 4);
    int*   degd  = (int*)alloc((size_t)N * 4);
    int*   off   = (int*)alloc((size_t)(N + 1) * 4);
    int*   partials = (int*)alloc(256 * 4);
    float* dsrc  = (float*)alloc((size_t)N * 4);
    float* ddst  = (float*)alloc((size_t)N * 4);
    float* tv    = (float*)alloc((size_t)N * 4);
    float* wfold = (float*)alloc(128 * 4);
    float* cval  = (float*)alloc(4);
    float* gsum  = (float*)alloc(N_GRAPHS * 4);
    float* gcnt  = (float*)alloc(N_GRAPHS * 4);
    __half* w1T  = (__half*)alloc(16384 * 2);
    __half* w2T  = (__half*)alloc(16384 * 2);
    (void)ws_size; (void)n_in; (void)out_size;

    const int half = nchunks * HBLK;                       // 256

    k_prep<<<3, 256, 0, stream>>>(W1, W2, W3, b3, Wout, bout, w1T, w2T, wfold, cval);

    // combined src+dst degree histograms (u16 per-block counts)
    k_hist2<<<2 * half, 512, 0, stream>>>(src, dst, ssrc, sdst, E, half);
    k_reduce2<<<(N + 255) / 256, 256, 0, stream>>>(ssrc, sdst, dsrc, degd, ddst, N);

    // CSR offsets
    const int nscan = (N + 1023) / 1024;
    k_scanA<<<nscan, 256, 0, stream>>>(degd, off, partials, N);
    k_scanB<<<1, 256, 0, stream>>>(partials, nscan, gsum, gcnt);
    k_scanC<<<nscan, 256, 0, stream>>>(off, partials, N, E);

    // in-place u16 prefix, then counting-sort fill (LDS atomics only)
    k_colscan16<<<(NBINS + 255) / 256, 256, 0, stream>>>(sdst, NBINS);
    k_csrfill2<<<half, 512, 0, stream>>>(src, dst, sdst, off, csr, E, N);

    const int gblocks = (N + 127) / 128;
    const int agblocks = (N + 7) / 8;

    // layer 1: M0 = (in_feat * dsrc) @ W1 ; M1 = prenorm(gather(M0), b1)
    k_gemm_mfma<2><<<gblocks, 512, 0, stream>>>(in_feat, M0, w1T, dsrc, N);
    k_gather_h<0><<<agblocks, 256, 0, stream>>>(M0, M1, csr, off, N, ddst, b1, dsrc, nullptr, nullptr);

    // layer 2: M0 = M1 @ W2 ; M1 = prenorm(gather(M0), b2)
    k_gemm_mfma<0><<<gblocks, 512, 0, stream>>>(M1, M0, w2T, nullptr, N);
    k_gather_h<0><<<agblocks, 256, 0, stream>>>(M0, M1, csr, off, N, ddst, b2, dsrc, nullptr, nullptr);

    // layer 3 (conv2 again): M0 = M1 @ W2 ; fused readout gather -> tv
    k_gemm_mfma<0><<<gblocks, 512, 0, stream>>>(M1, M0, w2T, nullptr, N);
    k_gather_h<1><<<agblocks, 256, 0, stream>>>(M0, nullptr, csr, off, N, ddst, b2, dsrc, wfold, tv);

    // readout aggregation + per-graph mean
    k_gather_final<<<(N + 255) / 256, 256, 0, stream>>>(tv, csr, off, ddst, gid, cval, gsum, gcnt, N);
    k_final<<<1, 128, 0, stream>>>(gsum, gcnt, out);
}